// Round 3
// baseline (305.880 us; speedup 1.0000x reference)
//
#include <hip/hip_runtime.h>

// Problem constants (from reference)
#define BSZ 512
#define NC  4
#define NN  16384
#define H2  (0.0078125f * 0.0078125f)   // H*H = 1/16384

#define BLK   512                       // threads per block (8 waves)
#define SPLIT 2                         // blocks per sample -> 1024 blocks
#define ELEMS_PER_BLOCK (NN / SPLIT)    // 8192 elements per block
#define ITERS (ELEMS_PER_BLOCK / BLK)   // 16 elements per thread

// Accumulator layout:
// acc[0..9]   = G upper triangle: 00,01,02,03,11,12,13,22,23,33
// acc[10..25] = T[i][m] = acc[10 + 4*i + m]

// Stage 1: one ELEMENT per thread per iteration.
//  - c[n], q0..q3[n]: coalesced dword loads (lane i -> element base+i)
//  - t4[n]:           coalesced dwordx4 (layout (B,N,C): float4 n = all 4
//                     channels of element n) -- round-2's t4[4i+j] pattern put
//                     lanes 64B apart (4x transaction amplification); this is 1x.
// Explicit depth-1 prefetch + unroll 1 keeps VGPR < 64 (8 waves/SIMD) while
// guaranteeing ~6 loads in flight per wave during the FMA block.
__global__ __launch_bounds__(BLK)
void loss_part(const float* __restrict__ coef,
               const float* __restrict__ pred,
               const float* __restrict__ targ,
               float* __restrict__ partial)
{
    const int blk = blockIdx.x;
    const int b   = blk / SPLIT;
    const int s   = blk % SPLIT;
    const int tid = threadIdx.x;

    const float* __restrict__ c  = coef + (size_t)b * NN;
    const float* __restrict__ q0 = pred + (size_t)b * NC * NN + 0 * NN;
    const float* __restrict__ q1 = pred + (size_t)b * NC * NN + 1 * NN;
    const float* __restrict__ q2 = pred + (size_t)b * NC * NN + 2 * NN;
    const float* __restrict__ q3 = pred + (size_t)b * NC * NN + 3 * NN;
    const float4* __restrict__ t4 = (const float4*)(targ + (size_t)b * NN * NC);

    float acc[26];
#pragma unroll
    for (int k = 0; k < 26; ++k) acc[k] = 0.f;

    int n = s * ELEMS_PER_BLOCK + tid;

    // prologue: prefetch element for iteration 0
    float  cN  = c[n];
    float  p0N = q0[n], p1N = q1[n], p2N = q2[n], p3N = q3[n];
    float4 tN  = t4[n];

#pragma unroll 1
    for (int k = 0; k < ITERS; ++k) {
        // rotate prefetched element into "current"
        const float  cc = cN;
        const float  p0 = p0N, p1 = p1N, p2 = p2N, p3 = p3N;
        const float4 tt = tN;

        // issue next element's loads BEFORE the FMA block (depth-1 pipeline)
        if (k + 1 < ITERS) {
            const int n2 = n + BLK;
            cN  = c[n2];
            p0N = q0[n2]; p1N = q1[n2]; p2N = q2[n2]; p3N = q3[n2];
            tN  = t4[n2];
            n   = n2;
        }

        const float a   = H2 * cc;
        const float ap0 = a * p0, ap1 = a * p1, ap2 = a * p2, ap3 = a * p3;
        // G block (depends on c,q only)
        acc[0]  += ap0 * p0;  acc[1]  += ap0 * p1;  acc[2]  += ap0 * p2;  acc[3]  += ap0 * p3;
        acc[4]  += ap1 * p1;  acc[5]  += ap1 * p2;  acc[6]  += ap1 * p3;
        acc[7]  += ap2 * p2;  acc[8]  += ap2 * p3;
        acc[9]  += ap3 * p3;
        // T block (consumes targets last so their waitcnt is deferred)
        acc[10] += ap0 * tt.x;  acc[11] += ap0 * tt.y;  acc[12] += ap0 * tt.z;  acc[13] += ap0 * tt.w;
        acc[14] += ap1 * tt.x;  acc[15] += ap1 * tt.y;  acc[16] += ap1 * tt.z;  acc[17] += ap1 * tt.w;
        acc[18] += ap2 * tt.x;  acc[19] += ap2 * tt.y;  acc[20] += ap2 * tt.z;  acc[21] += ap2 * tt.w;
        acc[22] += ap3 * tt.x;  acc[23] += ap3 * tt.y;  acc[24] += ap3 * tt.z;  acc[25] += ap3 * tt.w;
    }

    // Block reduction: wave shuffle -> LDS (8 waves) -> 26 threads write partials
    const int lane = tid & 63;
    const int wv   = tid >> 6;
    __shared__ float red[26][8];

#pragma unroll
    for (int k = 0; k < 26; ++k) {
        float v = acc[k];
#pragma unroll
        for (int o = 32; o > 0; o >>= 1) v += __shfl_down(v, o, 64);
        if (lane == 0) red[k][wv] = v;
    }
    __syncthreads();

    if (tid < 26) {
        float v = 0.f;
#pragma unroll
        for (int w = 0; w < 8; ++w) v += red[tid][w];
        partial[(size_t)blk * 26 + tid] = v;
    }
}

// Stage 2: one block, one thread per sample. Sum the SPLIT partials, run the
// 4x4 Gram-Schmidt solve per-thread, then reduce the mean across samples.
__global__ __launch_bounds__(BSZ)
void loss_final(const float* __restrict__ partial, float* __restrict__ out)
{
    const int b = threadIdx.x;   // BSZ = 512 threads, one per sample

    float s[26];
#pragma unroll
    for (int k = 0; k < 26; ++k) {
        float v = 0.f;
#pragma unroll
        for (int p = 0; p < SPLIT; ++p)
            v += partial[(size_t)(b * SPLIT + p) * 26 + k];
        s[k] = v;
    }

    float Gm[4][4];
    Gm[0][0] = s[0];
    Gm[0][1] = Gm[1][0] = s[1];
    Gm[0][2] = Gm[2][0] = s[2];
    Gm[0][3] = Gm[3][0] = s[3];
    Gm[1][1] = s[4];
    Gm[1][2] = Gm[2][1] = s[5];
    Gm[1][3] = Gm[3][1] = s[6];
    Gm[2][2] = s[7];
    Gm[2][3] = Gm[3][2] = s[8];
    Gm[3][3] = s[9];

    float Tm[4][4];
#pragma unroll
    for (int i = 0; i < 4; ++i)
#pragma unroll
        for (int m = 0; m < 4; ++m) Tm[i][m] = s[10 + 4 * i + m];

    // Modified Gram-Schmidt in 4-dim coefficient space.
    // u[j][*] = coefficients of orthonormal e_j in terms of p_0..p_3
    float u[4][4];
#pragma unroll
    for (int j = 0; j < 4; ++j) {
        float w[4];
#pragma unroll
        for (int i = 0; i < 4; ++i) w[i] = (i == j) ? 1.f : 0.f;
#pragma unroll
        for (int k = 0; k < 4; ++k) {
            if (k < j) {
                // proj = <v, e_k>_a = w^T G u_k  (modified GS: uses current w)
                float proj = 0.f;
#pragma unroll
                for (int i = 0; i < 4; ++i) {
                    float gu = 0.f;
#pragma unroll
                    for (int l = 0; l < 4; ++l) gu += Gm[i][l] * u[k][l];
                    proj += w[i] * gu;
                }
#pragma unroll
                for (int i = 0; i < 4; ++i) w[i] -= proj * u[k][i];
            }
        }
        float n2 = 0.f;
#pragma unroll
        for (int i = 0; i < 4; ++i) {
            float gw = 0.f;
#pragma unroll
            for (int l = 0; l < 4; ++l) gw += Gm[i][l] * w[l];
            n2 += w[i] * gw;
        }
        float sc = (n2 > 0.f) ? rsqrtf(n2) : 1.f;
#pragma unroll
        for (int i = 0; i < 4; ++i) u[j][i] = w[i] * sc;
    }

    // M[c][m] = sum_i u[c][i] * T[i][m]; per-sample loss = (4 - sum M^2)/4
    float ssum = 0.f;
#pragma unroll
    for (int c = 0; c < 4; ++c) {
#pragma unroll
        for (int m = 0; m < 4; ++m) {
            float M = 0.f;
#pragma unroll
            for (int i = 0; i < 4; ++i) M += u[c][i] * Tm[i][m];
            ssum += M * M;
        }
    }
    float ps = (4.f - ssum) * 0.25f;

    // Mean over 512 samples: wave shuffle -> LDS (8 waves) -> thread 0
    const int lane = b & 63;
    const int wv   = b >> 6;
#pragma unroll
    for (int o = 32; o > 0; o >>= 1) ps += __shfl_down(ps, o, 64);
    __shared__ float red[8];
    if (lane == 0) red[wv] = ps;
    __syncthreads();
    if (b == 0) {
        float tot = 0.f;
#pragma unroll
        for (int w = 0; w < 8; ++w) tot += red[w];
        out[0] = tot / (float)BSZ;
    }
}

extern "C" void kernel_launch(void* const* d_in, const int* in_sizes, int n_in,
                              void* d_out, int out_size, void* d_ws, size_t ws_size,
                              hipStream_t stream)
{
    const float* coef = (const float*)d_in[0];   // (B, N)
    const float* pred = (const float*)d_in[1];   // (B, C, N)
    const float* targ = (const float*)d_in[2];   // (B, N, C)
    float* out = (float*)d_out;                  // scalar
    float* partial = (float*)d_ws;               // (B*SPLIT, 26) partial sums

    loss_part<<<BSZ * SPLIT, BLK, 0, stream>>>(coef, pred, targ, partial);
    loss_final<<<1, BSZ, 0, stream>>>(partial, out);
}

// Round 4
// 274.227 us; speedup vs baseline: 1.1154x; 1.1154x over previous
//
#include <hip/hip_runtime.h>

// Problem constants (from reference)
#define BSZ 512
#define NC  4
#define NN  16384
#define H2  (0.0078125f * 0.0078125f)   // H*H = 1/16384

#define BLK   512                       // threads per block (8 waves)
#define SPLIT 2                         // blocks per sample -> 1024 blocks
#define ELEMS_PER_BLOCK (NN / SPLIT)    // 8192 elements per block
#define ITERS (ELEMS_PER_BLOCK / BLK)   // 16 elements per thread

typedef float f32x4 __attribute__((ext_vector_type(4)));

// Non-temporal load helpers: rounds 0/2/3 all plateaued at 2.44 TB/s effective
// ingest with a 50/50 HBM/L3 split (FETCH 147.5 MB of 288 MB). Theory: the
// 288 MB stream barely exceeds the 256 MB L3, so every dispatch pays full L3
// install+evict churn on top of the reads; 'nt' loads skip cache allocation.
__device__ __forceinline__ float ldnt(const float* p) {
    return __builtin_nontemporal_load(p);
}
__device__ __forceinline__ f32x4 ldnt4(const float* p) {
    return __builtin_nontemporal_load((const f32x4*)p);
}

// Accumulator layout:
// acc[0..9]   = G upper triangle: 00,01,02,03,11,12,13,22,23,33
// acc[10..25] = T[i][m] = acc[10 + 4*i + m]

// Stage 1: one ELEMENT per thread per iteration, all loads non-temporal.
//  - c[n], q0..q3[n]: coalesced dword loads
//  - t[n]:            coalesced dwordx4 ((B,N,C): float4 n = channels of elem n)
// Depth-1 prefetch; VGPR stays well under the 64-reg / 8-waves-per-SIMD cliff
// (round-1 lesson: never force occupancy with launch_bounds min-waves).
__global__ __launch_bounds__(BLK)
void loss_part(const float* __restrict__ coef,
               const float* __restrict__ pred,
               const float* __restrict__ targ,
               float* __restrict__ partial)
{
    const int blk = blockIdx.x;
    const int b   = blk / SPLIT;
    const int s   = blk % SPLIT;
    const int tid = threadIdx.x;

    const float* __restrict__ c  = coef + (size_t)b * NN;
    const float* __restrict__ q0 = pred + (size_t)b * NC * NN + 0 * NN;
    const float* __restrict__ q1 = pred + (size_t)b * NC * NN + 1 * NN;
    const float* __restrict__ q2 = pred + (size_t)b * NC * NN + 2 * NN;
    const float* __restrict__ q3 = pred + (size_t)b * NC * NN + 3 * NN;
    const float* __restrict__ tg = targ + (size_t)b * NN * NC;

    float acc[26];
#pragma unroll
    for (int k = 0; k < 26; ++k) acc[k] = 0.f;

    int n = s * ELEMS_PER_BLOCK + tid;

    // prologue: prefetch element for iteration 0
    float  cN  = ldnt(c + n);
    float  p0N = ldnt(q0 + n), p1N = ldnt(q1 + n), p2N = ldnt(q2 + n), p3N = ldnt(q3 + n);
    f32x4  tN  = ldnt4(tg + 4 * (size_t)n);

#pragma unroll 1
    for (int k = 0; k < ITERS; ++k) {
        // rotate prefetched element into "current"
        const float cc = cN;
        const float p0 = p0N, p1 = p1N, p2 = p2N, p3 = p3N;
        const f32x4 tt = tN;

        // issue next element's loads BEFORE the FMA block (depth-1 pipeline)
        if (k + 1 < ITERS) {
            const int n2 = n + BLK;
            cN  = ldnt(c + n2);
            p0N = ldnt(q0 + n2); p1N = ldnt(q1 + n2); p2N = ldnt(q2 + n2); p3N = ldnt(q3 + n2);
            tN  = ldnt4(tg + 4 * (size_t)n2);
            n   = n2;
        }

        const float a   = H2 * cc;
        const float ap0 = a * p0, ap1 = a * p1, ap2 = a * p2, ap3 = a * p3;
        // G block (depends on c,q only)
        acc[0]  += ap0 * p0;  acc[1]  += ap0 * p1;  acc[2]  += ap0 * p2;  acc[3]  += ap0 * p3;
        acc[4]  += ap1 * p1;  acc[5]  += ap1 * p2;  acc[6]  += ap1 * p3;
        acc[7]  += ap2 * p2;  acc[8]  += ap2 * p3;
        acc[9]  += ap3 * p3;
        // T block (consumes targets last so their waitcnt is deferred)
        acc[10] += ap0 * tt.x;  acc[11] += ap0 * tt.y;  acc[12] += ap0 * tt.z;  acc[13] += ap0 * tt.w;
        acc[14] += ap1 * tt.x;  acc[15] += ap1 * tt.y;  acc[16] += ap1 * tt.z;  acc[17] += ap1 * tt.w;
        acc[18] += ap2 * tt.x;  acc[19] += ap2 * tt.y;  acc[20] += ap2 * tt.z;  acc[21] += ap2 * tt.w;
        acc[22] += ap3 * tt.x;  acc[23] += ap3 * tt.y;  acc[24] += ap3 * tt.z;  acc[25] += ap3 * tt.w;
    }

    // Block reduction: wave shuffle -> LDS (8 waves) -> 26 threads write partials
    const int lane = tid & 63;
    const int wv   = tid >> 6;
    __shared__ float red[26][8];

#pragma unroll
    for (int k = 0; k < 26; ++k) {
        float v = acc[k];
#pragma unroll
        for (int o = 32; o > 0; o >>= 1) v += __shfl_down(v, o, 64);
        if (lane == 0) red[k][wv] = v;
    }
    __syncthreads();

    if (tid < 26) {
        float v = 0.f;
#pragma unroll
        for (int w = 0; w < 8; ++w) v += red[tid][w];
        partial[(size_t)blk * 26 + tid] = v;
    }
}

// Stage 2: one block, one thread per sample. Sum the SPLIT partials, run the
// 4x4 Gram-Schmidt solve per-thread, then reduce the mean across samples.
__global__ __launch_bounds__(BSZ)
void loss_final(const float* __restrict__ partial, float* __restrict__ out)
{
    const int b = threadIdx.x;   // BSZ = 512 threads, one per sample

    float s[26];
#pragma unroll
    for (int k = 0; k < 26; ++k) {
        float v = 0.f;
#pragma unroll
        for (int p = 0; p < SPLIT; ++p)
            v += partial[(size_t)(b * SPLIT + p) * 26 + k];
        s[k] = v;
    }

    float Gm[4][4];
    Gm[0][0] = s[0];
    Gm[0][1] = Gm[1][0] = s[1];
    Gm[0][2] = Gm[2][0] = s[2];
    Gm[0][3] = Gm[3][0] = s[3];
    Gm[1][1] = s[4];
    Gm[1][2] = Gm[2][1] = s[5];
    Gm[1][3] = Gm[3][1] = s[6];
    Gm[2][2] = s[7];
    Gm[2][3] = Gm[3][2] = s[8];
    Gm[3][3] = s[9];

    float Tm[4][4];
#pragma unroll
    for (int i = 0; i < 4; ++i)
#pragma unroll
        for (int m = 0; m < 4; ++m) Tm[i][m] = s[10 + 4 * i + m];

    // Modified Gram-Schmidt in 4-dim coefficient space.
    // u[j][*] = coefficients of orthonormal e_j in terms of p_0..p_3
    float u[4][4];
#pragma unroll
    for (int j = 0; j < 4; ++j) {
        float w[4];
#pragma unroll
        for (int i = 0; i < 4; ++i) w[i] = (i == j) ? 1.f : 0.f;
#pragma unroll
        for (int k = 0; k < 4; ++k) {
            if (k < j) {
                // proj = <v, e_k>_a = w^T G u_k  (modified GS: uses current w)
                float proj = 0.f;
#pragma unroll
                for (int i = 0; i < 4; ++i) {
                    float gu = 0.f;
#pragma unroll
                    for (int l = 0; l < 4; ++l) gu += Gm[i][l] * u[k][l];
                    proj += w[i] * gu;
                }
#pragma unroll
                for (int i = 0; i < 4; ++i) w[i] -= proj * u[k][i];
            }
        }
        float n2 = 0.f;
#pragma unroll
        for (int i = 0; i < 4; ++i) {
            float gw = 0.f;
#pragma unroll
            for (int l = 0; l < 4; ++l) gw += Gm[i][l] * w[l];
            n2 += w[i] * gw;
        }
        float sc = (n2 > 0.f) ? rsqrtf(n2) : 1.f;
#pragma unroll
        for (int i = 0; i < 4; ++i) u[j][i] = w[i] * sc;
    }

    // M[c][m] = sum_i u[c][i] * T[i][m]; per-sample loss = (4 - sum M^2)/4
    float ssum = 0.f;
#pragma unroll
    for (int c = 0; c < 4; ++c) {
#pragma unroll
        for (int m = 0; m < 4; ++m) {
            float M = 0.f;
#pragma unroll
            for (int i = 0; i < 4; ++i) M += u[c][i] * Tm[i][m];
            ssum += M * M;
        }
    }
    float ps = (4.f - ssum) * 0.25f;

    // Mean over 512 samples: wave shuffle -> LDS (8 waves) -> thread 0
    const int lane = b & 63;
    const int wv   = b >> 6;
#pragma unroll
    for (int o = 32; o > 0; o >>= 1) ps += __shfl_down(ps, o, 64);
    __shared__ float red[8];
    if (lane == 0) red[wv] = ps;
    __syncthreads();
    if (b == 0) {
        float tot = 0.f;
#pragma unroll
        for (int w = 0; w < 8; ++w) tot += red[w];
        out[0] = tot / (float)BSZ;
    }
}

extern "C" void kernel_launch(void* const* d_in, const int* in_sizes, int n_in,
                              void* d_out, int out_size, void* d_ws, size_t ws_size,
                              hipStream_t stream)
{
    const float* coef = (const float*)d_in[0];   // (B, N)
    const float* pred = (const float*)d_in[1];   // (B, C, N)
    const float* targ = (const float*)d_in[2];   // (B, N, C)
    float* out = (float*)d_out;                  // scalar
    float* partial = (float*)d_ws;               // (B*SPLIT, 26) partial sums

    loss_part<<<BSZ * SPLIT, BLK, 0, stream>>>(coef, pred, targ, partial);
    loss_final<<<1, BSZ, 0, stream>>>(partial, out);
}